// Round 1
// baseline (38.212 us; speedup 1.0000x reference)
//
#include <hip/hip_runtime.h>

// Problem constants
#define NSTEPS 255
#define TPTS   256          // time points incl t=0
#define NBLK   256          // integration blocks, 64 trajectories each
#define CH     15           // steps per prefetch chunk
// 17 chunks * 15 steps = 255 steps

#define GAMMA_F 0.36f
#define OMEGA_F 5.0265f
#define DT_F    0.00390625f          // 2^-8
#define CW      0.0375f              // sqrt(GAMMA)*sqrt(DT) = 0.6/16 (exact)

// ---- DPP wave64 sum: result lands in lane 63 ----
template<int CTRL, int RM>
__device__ __forceinline__ float dpp_add(float v) {
  int sh = __builtin_amdgcn_update_dpp(0, __float_as_int(v), CTRL, RM, 0xf, true);
  return v + __int_as_float(sh);
}

__device__ __forceinline__ float wave_sum64(float v) {
  v = dpp_add<0x111, 0xf>(v);  // row_shr:1
  v = dpp_add<0x112, 0xf>(v);  // row_shr:2
  v = dpp_add<0x114, 0xf>(v);  // row_shr:4
  v = dpp_add<0x118, 0xf>(v);  // row_shr:8  -> lane 15/31/47/63 hold row sums
  v = dpp_add<0x142, 0xa>(v);  // row_bcast:15 -> lane31 = r0+r1, lane63 = r2+r3
  v = dpp_add<0x143, 0xc>(v);  // row_bcast:31 -> lane63 = total
  return v;                    // valid in lane 63
}

// One step of Euler-Maruyama + per-step wave reduction + store from lane 63
#define STEP(w2, tidx) {                                                        \
  const float w0 = (w2).x * CW;                                                 \
  const float w1 = (w2).y * CW;                                                 \
  const float nx = x + meps_dt * y - (DT_F * GAMMA_F) * x - (x * z) * w0 - y * w1; \
  const float ny = y + eps_dt * x - (DT_F * OMEGA_F) * z - (DT_F * GAMMA_F) * y   \
                     - (y * z) * w0 + x * w1;                                   \
  const float nz = z + (DT_F * OMEGA_F) * y + (1.0f - z * z) * w0;              \
  x = nx; y = ny; z = nz;                                                       \
  const float sx = wave_sum64(x);                                               \
  const float sy = wave_sum64(y);                                               \
  const float sz = wave_sum64(z);                                               \
  if (lane == 63) {                                                             \
    float* p_ = pbase + (size_t)(tidx) * 3;                                     \
    p_[0] = sx; p_[1] = sy; p_[2] = sz;                                         \
  }                                                                             \
}

#define LOADC(BUF, CHUNK_) {                                                    \
  _Pragma("unroll")                                                             \
  for (int i_ = 0; i_ < CH; ++i_) BUF[i_] = wrow[(CHUNK_) * CH + i_];           \
}

#define PROC(BUF, TB) {                                                         \
  _Pragma("unroll")                                                             \
  for (int i_ = 0; i_ < CH; ++i_) STEP(BUF[i_], (TB) + i_)                      \
}

// grid = 256 blocks x 64 threads; block g integrates trajectories g*64..g*64+63
// partial layout: [256 blocks][256 timepoints][3 components], fp32 wave sums
__global__ __launch_bounds__(64) void sde_integrate(const float* __restrict__ inp,
                                                    const float* __restrict__ wvec,
                                                    float* __restrict__ partial) {
  const int g    = blockIdx.x;
  const int lane = threadIdx.x;
  // trajectory n = g*64+lane; eps = inputs[n % 32] = inputs[lane & 31]
  const float eps     = inp[lane & 31];
  const float meps_dt = -eps * DT_F;
  const float eps_dt  =  eps * DT_F;

  const float2* __restrict__ wrow =
      reinterpret_cast<const float2*>(wvec) + (size_t)(g * 64 + lane) * NSTEPS;
  float* __restrict__ pbase = partial + (size_t)g * (TPTS * 3);

  // t = 0: state is (0,0,1) for every trajectory -> wave sums (0,0,64)
  if (lane < 3) pbase[lane] = (lane == 2) ? 64.0f : 0.0f;

  float x = 0.0f, y = 0.0f, z = 1.0f;

  float2 bufA[CH], bufB[CH];   // static indexing only (regs, not scratch)

  LOADC(bufA, 0);
  int tb = 1;
  #pragma unroll 1
  for (int k = 0; k < 8; ++k) {
    LOADC(bufB, 2 * k + 1);    // prefetch next chunk while computing current
    PROC(bufA, tb); tb += CH;
    LOADC(bufA, 2 * k + 2);
    PROC(bufB, tb); tb += CH;
  }
  PROC(bufA, tb);              // chunk 16 (steps 240..254 -> t=241..255)
}

// one thread per (b, t): sum 8 wave-partials, emit 6 probabilities
__global__ __launch_bounds__(256) void sde_finalize(const float* __restrict__ partial,
                                                    float* __restrict__ out) {
  const int idx = blockIdx.x * blockDim.x + threadIdx.x;   // b*256 + t
  if (idx >= 32 * TPTS) return;
  const int b = idx >> 8;
  const int t = idx & 255;

  float sx = 0.0f, sy = 0.0f, sz = 0.0f;
  #pragma unroll
  for (int j = 0; j < 8; ++j) {
    const float* p = partial + (size_t)(((b * 8 + j) * TPTS) + t) * 3;
    sx += p[0]; sy += p[1]; sz += p[2];
  }
  const float inv = 1.0f / 512.0f;
  const float mx = sx * inv, my = sy * inv, mz = sz * inv;

  float* o = out + (size_t)idx * 6;
  o[0] = 0.5f * (1.0f + mx);
  o[1] = 0.5f * (1.0f - mx);
  o[2] = 0.5f * (1.0f + my);
  o[3] = 0.5f * (1.0f - my);
  o[4] = 0.5f * (1.0f + mz);
  o[5] = 0.5f * (1.0f - mz);
}

extern "C" void kernel_launch(void* const* d_in, const int* in_sizes, int n_in,
                              void* d_out, int out_size, void* d_ws, size_t ws_size,
                              hipStream_t stream) {
  (void)in_sizes; (void)n_in; (void)out_size; (void)ws_size;
  const float* inp  = (const float*)d_in[0];   // [32]
  const float* wvec = (const float*)d_in[1];   // [16384][255][2]
  float* out     = (float*)d_out;              // [32][256][6]
  float* partial = (float*)d_ws;               // needs 256*256*3*4 = 786432 B

  sde_integrate<<<NBLK, 64, 0, stream>>>(inp, wvec, partial);
  sde_finalize<<<32, 256, 0, stream>>>(partial, out);
}

// Round 3
// 30.663 us; speedup vs baseline: 1.2462x; 1.2462x over previous
//
#include <hip/hip_runtime.h>

// Problem constants
#define NSTEPS 255
#define TPTS   256          // time points incl t=0
#define NTRAJ  16384        // total trajectories
#define NBLK   256          // integration blocks, 64 trajectories each
#define CH     15           // steps per prefetch chunk; 17*15 = 255

#define GAMMA_F 0.36f
#define OMEGA_F 5.0265f
#define DT_F    0.00390625f          // 2^-8
#define CW      0.0375f              // sqrt(GAMMA)*sqrt(DT) = 0.6/16 (exact)

typedef __fp16 half2v __attribute__((ext_vector_type(2)));

// pack two f32 -> fp16x2 in one instruction (v_cvt_pkrtz_f16_f32)
__device__ __forceinline__ unsigned pk2(float a, float b) {
  half2v h = __builtin_amdgcn_cvt_pkrtz(a, b);
  return __builtin_bit_cast(unsigned, h);
}

// ---- DPP wave64 sum: result lands in lane 63 (used only in reduce kernel) ----
template<int CTRL, int RM>
__device__ __forceinline__ float dpp_add(float v) {
  int sh = __builtin_amdgcn_update_dpp(0, __float_as_int(v), CTRL, RM, 0xf, true);
  return v + __int_as_float(sh);
}

__device__ __forceinline__ float wave_sum64(float v) {
  v = dpp_add<0x111, 0xf>(v);  // row_shr:1
  v = dpp_add<0x112, 0xf>(v);  // row_shr:2
  v = dpp_add<0x114, 0xf>(v);  // row_shr:4
  v = dpp_add<0x118, 0xf>(v);  // row_shr:8
  v = dpp_add<0x142, 0xa>(v);  // row_bcast:15
  v = dpp_add<0x143, 0xc>(v);  // row_bcast:31 -> lane63 = total
  return v;                    // valid in lane 63
}

// One Euler-Maruyama step + packed fp16 store (no reduction in-loop).
// Store layout: buf[(t-1) * NTRAJ + n] = {pk(x,y), pk(z,0)}  (time-major)
#define STEP(w2, tidx) {                                                        \
  const float w0 = (w2).x * CW;                                                 \
  const float w1 = (w2).y * CW;                                                 \
  const float nx = x + meps_dt * y - (DT_F * GAMMA_F) * x - (x * z) * w0 - y * w1; \
  const float ny = y + eps_dt * x - (DT_F * OMEGA_F) * z - (DT_F * GAMMA_F) * y   \
                     - (y * z) * w0 + x * w1;                                   \
  const float nz = z + (DT_F * OMEGA_F) * y + (1.0f - z * z) * w0;              \
  x = nx; y = ny; z = nz;                                                       \
  sp[(size_t)((tidx) - 1) * NTRAJ] = make_uint2(pk2(x, y), pk2(z, 0.0f));       \
}

#define LOADC(BUF, CHUNK_) {                                                    \
  _Pragma("unroll")                                                             \
  for (int i_ = 0; i_ < CH; ++i_) BUF[i_] = wrow[(CHUNK_) * CH + i_];           \
}

#define PROC(BUF, TB) {                                                         \
  _Pragma("unroll")                                                             \
  for (int i_ = 0; i_ < CH; ++i_) STEP(BUF[i_], (TB) + i_)                      \
}

// grid = 256 blocks x 64 threads; block g integrates trajectories g*64..g*64+63
__global__ __launch_bounds__(64) void sde_integrate(const float* __restrict__ inp,
                                                    const float* __restrict__ wvec,
                                                    uint2* __restrict__ buf) {
  const int g    = blockIdx.x;
  const int lane = threadIdx.x;
  // trajectory n = g*64+lane; eps = inputs[n % 32] = inputs[lane & 31]
  const float eps     = inp[lane & 31];
  const float meps_dt = -eps * DT_F;
  const float eps_dt  =  eps * DT_F;

  const float2* __restrict__ wrow =
      reinterpret_cast<const float2*>(wvec) + (size_t)(g * 64 + lane) * NSTEPS;
  uint2* __restrict__ sp = buf + (size_t)(g * 64 + lane);

  float x = 0.0f, y = 0.0f, z = 1.0f;

  float2 bufA[CH], bufB[CH];   // static indexing only (regs, not scratch)

  LOADC(bufA, 0);
  int tb = 1;
  #pragma unroll 1
  for (int k = 0; k < 8; ++k) {
    LOADC(bufB, 2 * k + 1);    // prefetch next chunk while computing current
    PROC(bufA, tb); tb += CH;
    LOADC(bufA, 2 * k + 2);
    PROC(bufB, tb); tb += CH;
  }
  PROC(bufA, tb);              // chunk 16 (steps 240..254 -> t=241..255)
}

// One wave per (b, t) pair: sum 512 trajectories' fp16 states, emit 6 probs.
// 8192 waves = 2048 blocks x 256 threads -> full occupancy, coalesced reads.
__global__ __launch_bounds__(256) void sde_reduce(const uint2* __restrict__ buf,
                                                  float* __restrict__ out) {
  const int wid  = (blockIdx.x << 2) | (threadIdx.x >> 6);   // 0..8191 = b*256+t
  const int lane = threadIdx.x & 63;
  const int b = wid >> 8;
  const int t = wid & 255;
  float* o = out + (size_t)wid * 6;

  if (t == 0) {
    // exact initial state (0,0,1): probs = {0.5, 0.5, 0.5, 0.5, 1, 0}
    if (lane < 6) o[lane] = (lane == 4) ? 1.0f : ((lane == 5) ? 0.0f : 0.5f);
    return;
  }

  const uint2* base = buf + (size_t)(t - 1) * NTRAJ + (b << 9) + lane;
  float sx = 0.0f, sy = 0.0f, sz = 0.0f;
  #pragma unroll
  for (int k = 0; k < 8; ++k) {                 // sample n = b*512 + k*64 + lane
    const uint2 v = base[(size_t)k * 64];       // contiguous 512B per instr
    const half2v xy = __builtin_bit_cast(half2v, v.x);
    const half2v zp = __builtin_bit_cast(half2v, v.y);
    sx += (float)xy[0];
    sy += (float)xy[1];
    sz += (float)zp[0];
  }
  sx = wave_sum64(sx);
  sy = wave_sum64(sy);
  sz = wave_sum64(sz);

  if (lane == 63) {
    const float inv = 1.0f / 512.0f;
    const float mx = sx * inv, my = sy * inv, mz = sz * inv;
    o[0] = 0.5f * (1.0f + mx);
    o[1] = 0.5f * (1.0f - mx);
    o[2] = 0.5f * (1.0f + my);
    o[3] = 0.5f * (1.0f - my);
    o[4] = 0.5f * (1.0f + mz);
    o[5] = 0.5f * (1.0f - mz);
  }
}

extern "C" void kernel_launch(void* const* d_in, const int* in_sizes, int n_in,
                              void* d_out, int out_size, void* d_ws, size_t ws_size,
                              hipStream_t stream) {
  (void)in_sizes; (void)n_in; (void)out_size; (void)ws_size;
  const float* inp  = (const float*)d_in[0];   // [32]
  const float* wvec = (const float*)d_in[1];   // [16384][255][2]
  float* out  = (float*)d_out;                 // [32][256][6]
  uint2* buf  = (uint2*)d_ws;                  // 255*16384*8 B = 33.4 MB packed fp16 states

  sde_integrate<<<NBLK, 64, 0, stream>>>(inp, wvec, buf);
  sde_reduce<<<2048, 256, 0, stream>>>(buf, out);
}

// Round 4
// 27.814 us; speedup vs baseline: 1.3739x; 1.1025x over previous
//
#include <hip/hip_runtime.h>

// Problem constants
#define NSTEPS 255
#define TPTS   256          // time points incl t=0
#define NTRAJ  16384        // total trajectories
#define NBLK   256          // integration blocks, 64 trajectories each
#define CH     15           // steps per prefetch chunk; 17*15 = 255

#define GAMMA_F 0.36f
#define OMEGA_F 5.0265f
#define DT_F    0.00390625f          // 2^-8
#define CW      0.0375f              // sqrt(GAMMA)*sqrt(DT) = 0.6/16 (exact)
#define GD      (GAMMA_F * DT_F)
#define OD      (OMEGA_F * DT_F)

typedef __fp16 half2v __attribute__((ext_vector_type(2)));
typedef float  f32x2  __attribute__((ext_vector_type(2)));

// pack two f32 -> fp16x2 in one instruction (v_cvt_pkrtz_f16_f32)
__device__ __forceinline__ unsigned pk2(float a, float b) {
  half2v h = __builtin_amdgcn_cvt_pkrtz(a, b);
  return __builtin_bit_cast(unsigned, h);
}

// ---- DPP wave64 sum: result lands in lane 63 (used only in reduce kernel) ----
template<int CTRL, int RM>
__device__ __forceinline__ float dpp_add(float v) {
  int sh = __builtin_amdgcn_update_dpp(0, __float_as_int(v), CTRL, RM, 0xf, true);
  return v + __int_as_float(sh);
}

__device__ __forceinline__ float wave_sum64(float v) {
  v = dpp_add<0x111, 0xf>(v);  // row_shr:1
  v = dpp_add<0x112, 0xf>(v);  // row_shr:2
  v = dpp_add<0x114, 0xf>(v);  // row_shr:4
  v = dpp_add<0x118, 0xf>(v);  // row_shr:8
  v = dpp_add<0x142, 0xa>(v);  // row_bcast:15
  v = dpp_add<0x143, 0xc>(v);  // row_bcast:31 -> lane63 = total
  return v;                    // valid in lane 63
}

// One Euler-Maruyama step, packed-f32 form. State: v = (x,y), z scalar.
//   nx = x - eps*dt*y - GD*x - (x*z)*w0 - y*w1
//   ny = y + eps*dt*x - OD*z - GD*y - (y*z)*w0 + x*w1
//   nz = z + OD*y + (1 - z*z)*w0
// (nx,ny) as 5 pk-FMA (+1 scalar fma for the -OD*z term); nz scalar.
#define STEP(w2, tidx) {                                                        \
  const float w0  = (w2).x * CW;                                                \
  const f32x2 w1n = nCW2 * (w2).y;             /* (-CW*wy, +CW*wy) */           \
  const f32x2 sw  = __builtin_shufflevector(v, v, 1, 0);   /* (y,x) */          \
  f32x2 t = __builtin_elementwise_fma(epack, sw, v);                            \
  t = __builtin_elementwise_fma(mGD2, v, t);                                    \
  const f32x2 p   = v * z;                                                      \
  const f32x2 mw0 = {-w0, -w0};                                                 \
  t = __builtin_elementwise_fma(p, mw0, t);                                     \
  t = __builtin_elementwise_fma(sw, w1n, t);                                    \
  t[1] = __builtin_fmaf(-OD, z, t[1]);                                          \
  const float a = __builtin_fmaf(OD, v[1], z);                                  \
  const float r = __builtin_fmaf(-(z * z), w0, w0);                             \
  v = t; z = a + r;                                                             \
  sp[(size_t)((tidx) - 1) * NTRAJ] = make_uint2(pk2(v[0], v[1]), pk2(z, 0.0f)); \
}

#define LOADC(BUF, CHUNK_) {                                                    \
  _Pragma("unroll")                                                             \
  for (int i_ = 0; i_ < CH; ++i_) BUF[i_] = wrow[(CHUNK_) * CH + i_];           \
}

#define PROC(BUF) {                                                             \
  _Pragma("unroll")                                                             \
  for (int i_ = 0; i_ < CH; ++i_) STEP(BUF[i_], tb + i_)                        \
  tb += CH;                                                                     \
}

// grid = 256 blocks x 64 threads; block g integrates trajectories g*64..g*64+63
// Store layout: buf[(t-1) * NTRAJ + n] = {pk(x,y), pk(z,0)}  (time-major)
__global__ __launch_bounds__(64) void sde_integrate(const float* __restrict__ inp,
                                                    const float* __restrict__ wvec,
                                                    uint2* __restrict__ buf) {
  const int g    = blockIdx.x;
  const int lane = threadIdx.x;
  // trajectory n = g*64+lane; eps = inputs[n % 32] = inputs[lane & 31]
  const float eps = inp[lane & 31];
  const f32x2 epack = {-eps * DT_F, eps * DT_F};
  const f32x2 mGD2  = {-GD, -GD};
  const f32x2 nCW2  = {-CW, CW};

  const float2* __restrict__ wrow =
      reinterpret_cast<const float2*>(wvec) + (size_t)(g * 64 + lane) * NSTEPS;
  uint2* __restrict__ sp = buf + (size_t)(g * 64 + lane);

  f32x2 v = {0.0f, 0.0f};
  float z = 1.0f;

  float2 bufA[CH], bufB[CH], bufC[CH];   // static indexing only (regs)

  // prefetch distance 2: chunks c and c+1 in flight before computing c
  LOADC(bufA, 0);
  LOADC(bufB, 1);
  int tb = 1;
  #pragma unroll 1
  for (int k = 0; k < 5; ++k) {          // chunks 3k..3k+2, loads 3k+2..3k+4
    LOADC(bufC, 3 * k + 2); PROC(bufA);
    LOADC(bufA, 3 * k + 3); PROC(bufB);
    LOADC(bufB, 3 * k + 4); PROC(bufC);
  }
  PROC(bufA);                            // chunk 15
  PROC(bufB);                            // chunk 16
}

// One wave per (b, t) pair: sum 512 trajectories' fp16 states, emit 6 probs.
// 8192 waves = 2048 blocks x 256 threads -> full occupancy, coalesced reads.
__global__ __launch_bounds__(256) void sde_reduce(const uint2* __restrict__ buf,
                                                  float* __restrict__ out) {
  const int wid  = (blockIdx.x << 2) | (threadIdx.x >> 6);   // 0..8191 = b*256+t
  const int lane = threadIdx.x & 63;
  const int b = wid >> 8;
  const int t = wid & 255;
  float* o = out + (size_t)wid * 6;

  if (t == 0) {
    // exact initial state (0,0,1): probs = {0.5, 0.5, 0.5, 0.5, 1, 0}
    if (lane < 6) o[lane] = (lane == 4) ? 1.0f : ((lane == 5) ? 0.0f : 0.5f);
    return;
  }

  const uint2* base = buf + (size_t)(t - 1) * NTRAJ + (b << 9) + lane;
  float sx = 0.0f, sy = 0.0f, sz = 0.0f;
  #pragma unroll
  for (int k = 0; k < 8; ++k) {                 // sample n = b*512 + k*64 + lane
    const uint2 w = base[(size_t)k * 64];       // contiguous 512B per instr
    const half2v xy = __builtin_bit_cast(half2v, w.x);
    const half2v zp = __builtin_bit_cast(half2v, w.y);
    sx += (float)xy[0];
    sy += (float)xy[1];
    sz += (float)zp[0];
  }
  sx = wave_sum64(sx);
  sy = wave_sum64(sy);
  sz = wave_sum64(sz);

  if (lane == 63) {
    const float inv = 1.0f / 512.0f;
    const float mx = sx * inv, my = sy * inv, mz = sz * inv;
    o[0] = 0.5f * (1.0f + mx);
    o[1] = 0.5f * (1.0f - mx);
    o[2] = 0.5f * (1.0f + my);
    o[3] = 0.5f * (1.0f - my);
    o[4] = 0.5f * (1.0f + mz);
    o[5] = 0.5f * (1.0f - mz);
  }
}

extern "C" void kernel_launch(void* const* d_in, const int* in_sizes, int n_in,
                              void* d_out, int out_size, void* d_ws, size_t ws_size,
                              hipStream_t stream) {
  (void)in_sizes; (void)n_in; (void)out_size; (void)ws_size;
  const float* inp  = (const float*)d_in[0];   // [32]
  const float* wvec = (const float*)d_in[1];   // [16384][255][2]
  float* out  = (float*)d_out;                 // [32][256][6]
  uint2* buf  = (uint2*)d_ws;                  // 255*16384*8 B = 33.4 MB packed fp16 states

  sde_integrate<<<NBLK, 64, 0, stream>>>(inp, wvec, buf);
  sde_reduce<<<2048, 256, 0, stream>>>(buf, out);
}